// Round 5
// baseline (16461.014 us; speedup 1.0000x reference)
//
#include <hip/hip_runtime.h>

typedef __attribute__((ext_vector_type(8))) short bf8v;   // 8 x bf16
typedef __attribute__((ext_vector_type(4))) float fx4;    // MFMA accumulator
typedef unsigned short u16;
typedef unsigned int u32;

constexpr int SP = 1032;     // padded LDS row stride in elements (16B-aligned rows, spread banks)

__device__ __forceinline__ float b2f(u16 h) {
    u32 u = ((u32)h) << 16; float f; __builtin_memcpy(&f, &u, 4); return f;
}
__device__ __forceinline__ u16 f2b(float f) {
    u32 u; __builtin_memcpy(&u, &f, 4);
    return (u16)((u + 0x7fffu + ((u >> 16) & 1u)) >> 16);
}

// runtime-dtype scalar / 8-wide loads (one-time paths only)
__device__ __forceinline__ float ldsc(const void* p, long off, bool f32) {
    return f32 ? ((const float*)p)[off] : b2f(((const u16*)p)[off]);
}
__device__ __forceinline__ bf8v ld8cv(const void* p, long off, bool f32) {
    if (!f32) return *(const bf8v*)((const u16*)p + off);
    const float* f = (const float*)p + off;
    bf8v r;
#pragma unroll
    for (int j = 0; j < 8; ++j) r[j] = (short)f2b(f[j]);
    return r;
}

__device__ __forceinline__ float gru_out(float sr, float sz, float sn, float xn,
                                         float bxr, float bxz, float bxn,
                                         float bhr, float bhz, float bhn, float hp) {
    float r = 1.f / (1.f + __expf(-(sr + bxr + bhr)));
    float z = 1.f / (1.f + __expf(-(sz + bxz + bhz)));
    float pn = xn + bxn + r * (sn + bhn);
    pn = fminf(fmaxf(pn, -15.f), 15.f);
    float e = __expf(2.f * pn);
    float n = (e - 1.f) / (e + 1.f);
    return n + z * (hp - n);
}

// ---------------------------------------------------------------- zero helpers
__global__ __launch_bounds__(256) void zero_a(uint4* __restrict__ p) {    // 32 blocks: 131072 B (zbuf)
    p[(long)blockIdx.x * 256 + threadIdx.x] = make_uint4(0u, 0u, 0u, 0u);
}
__global__ __launch_bounds__(256) void zero_misc(uint4* __restrict__ p) { // 5 blocks: 20480 B (misc+bflags)
    p[(long)blockIdx.x * 256 + threadIdx.x] = make_uint4(0u, 0u, 0u, 0u);
}

// ---------------------------------------------------------------- flags[0]: 1 = inputs fp32
__global__ __launch_bounds__(256) void detect_dtype(const u32* __restrict__ x,
                                                    u32* __restrict__ flags) {
    __shared__ int red[256];
    int t = threadIdx.x;
    int cnt = 0;
    for (int i = t; i < 4096; i += 256) {
        u32 ex = (x[i] >> 7) & 0xff;
        cnt += (ex >= 100 && ex <= 135) ? 1 : 0;
    }
    red[t] = cnt; __syncthreads();
    for (int s = 128; s > 0; s >>= 1) { if (t < s) red[t] += red[t + s]; __syncthreads(); }
    if (t == 0) flags[0] = (red[0] < 2048) ? 1u : 0u;
}

// ---------------------------------------------------------------- x -> bf16 once (layout preserved)
__global__ __launch_bounds__(256) void conv_x(const void* __restrict__ x, u16* __restrict__ xc,
                                              const u32* __restrict__ flags) {
    bool f32 = flags[0] != 0;
    long i = ((long)blockIdx.x * 256 + threadIdx.x) * 8;
    if (f32) {
        const float* xf = (const float*)x + i;
        union { u16 o[8]; uint4 v; } u;
#pragma unroll
        for (int j = 0; j < 8; ++j) u.o[j] = f2b(xf[j]);
        *(uint4*)&xc[i] = u.v;
    } else {
        *(uint4*)&xc[i] = *(const uint4*)((const u16*)x + i);
    }
}

// ---------------------------------------------------------------- contention-free grid barrier (256 blocks)
// Each block release-stores its own flag line; block 0's 256 threads poll one flag each,
// then block 0 release-stores gen; one thread/block polls gen (acquire covers the CU's caches).
// Bounded spins (deadlock insurance): if co-residency ever fails, waits time out
// (~1M poll iters first, then 4K once degraded) so the kernel completes with wrong
// results instead of hanging the container. Healthy waits are ~100s of iters -> never trips.
__device__ __forceinline__ void gbar(u32* bflags, u32* gen, u32 target, int& degraded) {
    const int LIM = degraded ? (1 << 12) : (1 << 20);
    __syncthreads();
    if (threadIdx.x == 0)
        __hip_atomic_store(&bflags[(u32)blockIdx.x * 16u], target,
                           __ATOMIC_RELEASE, __HIP_MEMORY_SCOPE_AGENT);
    if (blockIdx.x == 0) {
        int it = 0;
        while (__hip_atomic_load(&bflags[(u32)threadIdx.x * 16u],
                                 __ATOMIC_ACQUIRE, __HIP_MEMORY_SCOPE_AGENT) < target) {
            __builtin_amdgcn_s_sleep(1);
            if (++it > LIM) { degraded = 1; break; }
        }
        __syncthreads();
        if (threadIdx.x == 0)
            __hip_atomic_store(gen, target, __ATOMIC_RELEASE, __HIP_MEMORY_SCOPE_AGENT);
    }
    if (threadIdx.x == 0) {
        int it = 0;
        while (__hip_atomic_load(gen, __ATOMIC_ACQUIRE, __HIP_MEMORY_SCOPE_AGENT) < target) {
            __builtin_amdgcn_s_sleep(2);
            if (++it > LIM) { degraded = 1; break; }
        }
    }
    __syncthreads();
}

// ================================================================ per-timestep worker
// LDS bands (48 rows x SP, bf16, units u0..u0+7 of this block):
//   rows  0..15 : Wh [r(0-7) | z(8-15)]
//   rows 16..31 : Wx [r(0-7) | z(8-15)]
//   rows 32..47 : N  [Whn(0-7) | Wxn(8-15)]
// MFMA 16x16x32: A row = batch (l15), B col = l15, acc row = lk*4+reg, col = l15.
// accRZ = h@WhRZ + x@WxRZ (cols: 0-7 = sr, 8-15 = sz)
// accNH = h@N (cols 0-7 = sn valid) ; accNX = x@N (cols 8-15 = xn valid)
template<bool XF32>
__device__ __forceinline__ void gru_step(const short* __restrict__ Wlds,
    const u16* __restrict__ hprev, u16* __restrict__ hout,
    const void* __restrict__ xsrc, long xrow, long hrow,
    int l15, int lk, int bb, int u0,
    float Bxr, float Bxz, float Bxn, float Bhr, float Bhz, float Bhn)
{
    const int koff = lk * 8;

    bf8v bh[4], bx[4];
#pragma unroll
    for (int p = 0; p < 4; ++p) {
        bh[p] = *(const bf8v*)&hprev[hrow + p * 32 + koff];
        if constexpr (XF32) {
            const float* xf = (const float*)xsrc + xrow + p * 32 + koff;
            bf8v tv;
#pragma unroll
            for (int j = 0; j < 8; ++j) tv[j] = (short)f2b(xf[j]);
            bx[p] = tv;
        } else {
            bx[p] = *(const bf8v*)((const u16*)xsrc + xrow + p * 32 + koff);
        }
    }

    fx4 accRZ = {0.f, 0.f, 0.f, 0.f};
    fx4 accNH = {0.f, 0.f, 0.f, 0.f};
    fx4 accNX = {0.f, 0.f, 0.f, 0.f};

#pragma unroll
    for (int i = 0; i < 32; ++i) {
        const int kk = i * 32;
        bf8v rzH = *(const bf8v*)&Wlds[l15 * SP + kk + koff];
        bf8v rzX = *(const bf8v*)&Wlds[(16 + l15) * SP + kk + koff];
        bf8v nW  = *(const bf8v*)&Wlds[(32 + l15) * SP + kk + koff];
        bf8v aH = bh[i & 3], aX = bx[i & 3];
        if (i + 4 < 32) {                       // 4-deep prefetch hides L2/L3 latency
            bh[i & 3] = *(const bf8v*)&hprev[hrow + kk + 128 + koff];
            if constexpr (XF32) {
                const float* xf = (const float*)xsrc + xrow + kk + 128 + koff;
                bf8v tv;
#pragma unroll
                for (int j = 0; j < 8; ++j) tv[j] = (short)f2b(xf[j]);
                bx[i & 3] = tv;
            } else {
                bx[i & 3] = *(const bf8v*)((const u16*)xsrc + xrow + kk + 128 + koff);
            }
        }
        accRZ = __builtin_amdgcn_mfma_f32_16x16x32_bf16(aH, rzH, accRZ, 0, 0, 0);
        accRZ = __builtin_amdgcn_mfma_f32_16x16x32_bf16(aX, rzX, accRZ, 0, 0, 0);
        accNH = __builtin_amdgcn_mfma_f32_16x16x32_bf16(aH, nW,  accNH, 0, 0, 0);
        accNX = __builtin_amdgcn_mfma_f32_16x16x32_bf16(aX, nW,  accNX, 0, 0, 0);
    }

#pragma unroll
    for (int reg = 0; reg < 4; ++reg) {
        float sz = __shfl_xor(accRZ[reg], 8);   // z-gate from lane l15+8
        float xn = __shfl_xor(accNX[reg], 8);   // x@Wxn from lane l15+8
        if (l15 < 8) {
            const int bi = bb + lk * 4 + reg;
            const long ho = (long)bi * 1024 + u0 + l15;
            float hp = b2f(hprev[ho]);
            float hv = gru_out(accRZ[reg], sz, accNH[reg], xn,
                               Bxr, Bxz, Bxn, Bhr, Bhz, Bhn, hp);
            hout[ho] = f2b(hv);
        }
    }
}

// ================================================================ persistent two-layer GRU
// 256 blocks x 256 threads, 1 block/CU (99 KB LDS). blk: layer = blk>>7, units u0 = (blk&127)*8.
// Weights LDS-resident (staged once, fp32->bf16 converted at load). Waves = 4 batch quarters.
// Time-skew: iteration s = layer0 step s, layer1 step s-1; one grid barrier per iteration.
__device__ void persist_impl(short* Wlds, bool wf32, bool xf32,
    const void* x, const u16* x16,
    const void* Wx0, const void* Wh0, const void* bx0, const void* bh0,
    const void* Wx1, const void* Wh1, const void* bx1, const void* bh1,
    const u16* zbuf, u16* h0a, u16* h0b, u16* h1a, u16* h1b,
    u32* bflags, u32* gen)
{
    const int blk = blockIdx.x;
    const int layer = blk >> 7;
    const int u0 = (blk & 127) * 8;
    const int tid = threadIdx.x;
    const int l = tid & 63, l15 = l & 15, lk = l >> 4;
    const int w = tid >> 6, bb = w * 16;

    const void* Wh  = layer ? Wh1 : Wh0;
    const void* Wx  = layer ? Wx1 : Wx0;
    const void* bxp = layer ? bx1 : bx0;
    const void* bhp = layer ? bh1 : bh0;

    // ---- stage weight slice into LDS once (16 rz-rows x 128 chunks of 8)
    for (int c = tid; c < 16 * 128; c += 256) {
        int r = c >> 7;                 // 0..15
        int kc = (c & 127) * 8;
        int g = r >> 3, j = r & 7;      // g: 0=r-gate, 1=z-gate
        long go = (long)(g * 1024 + u0 + j) * 1024 + kc;
        *(bf8v*)&Wlds[r * SP + kc]        = ld8cv(Wh, go, wf32);
        *(bf8v*)&Wlds[(16 + r) * SP + kc] = ld8cv(Wx, go, wf32);
        long gn = (long)(2048 + u0 + j) * 1024 + kc;          // n-gate row
        const void* Wn = (r < 8) ? Wh : Wx;                   // [Whn | Wxn] packed band
        *(bf8v*)&Wlds[(32 + r) * SP + kc] = ld8cv(Wn, gn, wf32);
    }

    // ---- hoist biases (per-lane unit u0 + (l15&7))
    const int uu = u0 + (l15 & 7);
    float Bxr = ldsc(bxp, uu, wf32),        Bhr = ldsc(bhp, uu, wf32);
    float Bxz = ldsc(bxp, 1024 + uu, wf32), Bhz = ldsc(bhp, 1024 + uu, wf32);
    float Bxn = ldsc(bxp, 2048 + uu, wf32), Bhn = ldsc(bhp, 2048 + uu, wf32);
    __syncthreads();

    u16* h0buf[2] = { h0a, h0b };
    u16* h1buf[2] = { h1a, h1b };
    const long hrow = (long)(bb + l15) * 1024;
    int degraded = 0;

    for (int s = 0; s <= 512; ++s) {
        const int t = layer ? (s - 1) : s;
        const bool active = layer ? (s >= 1) : (s < 512);
        if (active) {
            const u16* hprev = (t == 0) ? zbuf
                             : (layer ? h1buf[(t + 1) & 1] : h0buf[(t + 1) & 1]);
            u16* hout = layer ? h1buf[t & 1] : h0buf[t & 1];
            if (layer) {
                gru_step<false>(Wlds, hprev, hout, h0buf[t & 1], hrow, hrow,
                                l15, lk, bb, u0, Bxr, Bxz, Bxn, Bhr, Bhz, Bhn);
            } else {
                const long xrow = ((long)(bb + l15) * 512 + t) * 1024;
                if (xf32)
                    gru_step<true>(Wlds, hprev, hout, x, xrow, hrow,
                                   l15, lk, bb, u0, Bxr, Bxz, Bxn, Bhr, Bhz, Bhn);
                else
                    gru_step<false>(Wlds, hprev, hout, x16, xrow, hrow,
                                    l15, lk, bb, u0, Bxr, Bxz, Bxn, Bhr, Bhz, Bhn);
            }
        }
        gbar(bflags, gen, (u32)(s + 1), degraded);
    }
}

__global__ __launch_bounds__(256, 1) void gru_persist(const void* x, const u16* xc, int xconv,
    const void* Wx0, const void* Wh0, const void* bx0, const void* bh0,
    const void* Wx1, const void* Wh1, const void* bx1, const void* bh1,
    const u16* zbuf, u16* h0a, u16* h0b, u16* h1a, u16* h1b,
    const u32* flags, u32* bflags, u32* gen)
{
    __shared__ __align__(16) short Wlds[48 * SP];    // 99072 B -> 1 block/CU
    bool wf32 = flags[0] != 0;
    bool xf32 = wf32 && !xconv;                      // fallback: stream fp32 x with on-the-fly convert
    const u16* x16 = xconv ? xc : (const u16*)x;
    persist_impl(Wlds, wf32, xf32, x, x16,
                 Wx0, Wh0, bx0, bh0, Wx1, Wh1, bx1, bh1,
                 zbuf, h0a, h0b, h1a, h1b, bflags, gen);
}

// ---------------------------------------------------------------- final FC: fp32 output
__global__ __launch_bounds__(256) void fc_out(const u16* __restrict__ h,
                                              const void* __restrict__ fcW,
                                              const void* __restrict__ fcb,
                                              const u32* __restrict__ flags,
                                              float* __restrict__ out) {
    bool f32 = flags[0] != 0;
    __shared__ float red[256];
    int t = threadIdx.x, b = t >> 2, q = t & 3;
    float s = 0.f;
    for (int u = q * 256; u < q * 256 + 256; ++u) {
        float wv = f32 ? ((const float*)fcW)[u] : b2f(((const u16*)fcW)[u]);
        s += b2f(h[(long)b * 1024 + u]) * wv;
    }
    red[t] = s; __syncthreads();
    if (q == 0) {
        float fb = f32 ? ((const float*)fcb)[0] : b2f(((const u16*)fcb)[0]);
        out[b] = red[t] + red[t + 1] + red[t + 2] + red[t + 3] + fb;
    }
}

// ================================================================ host
extern "C" void kernel_launch(void* const* d_in, const int* in_sizes, int n_in,
                              void* d_out, int out_size, void* d_ws, size_t ws_size,
                              hipStream_t stream) {
    (void)in_sizes; (void)n_in; (void)out_size;
    char* ws = (char*)d_ws;
    u16* zbuf = (u16*)ws;                  // 131072 B zeros (initial h)
    u16* h0a  = (u16*)(ws + 131072);
    u16* h0b  = (u16*)(ws + 262144);
    u16* h1a  = (u16*)(ws + 393216);
    u16* h1b  = (u16*)(ws + 524288);
    u32* misc = (u32*)(ws + 655360);       // 4096 B: flags + gen
    u32* flags = misc;                     // [0..7]
    u32* gen   = misc + 16;                // own cacheline
    u32* bflags = (u32*)(ws + 659456);     // 16384 B: 256 flags x 64 B stride
    u16* xc    = (u16*)(ws + 675840);      // 67108864 B: bf16 x (optional)
    const size_t NEED = 675840ull + 67108864ull;
    const int xconv = (ws_size >= NEED) ? 1 : 0;

    zero_a<<<32, 256, 0, stream>>>((uint4*)d_ws);
    zero_misc<<<5, 256, 0, stream>>>((uint4*)(ws + 655360));
    detect_dtype<<<1, 256, 0, stream>>>((const u32*)d_in[0], flags);
    if (xconv) conv_x<<<16384, 256, 0, stream>>>(d_in[0], xc, flags);

    gru_persist<<<256, 256, 0, stream>>>(d_in[0], xc, xconv,
        d_in[1], d_in[3], d_in[2], d_in[4],      // Wx0, Wh0, bx0, bh0
        d_in[5], d_in[7], d_in[6], d_in[8],      // Wx1, Wh1, bx1, bh1
        zbuf, h0a, h0b, h1a, h1b, flags, bflags, gen);

    fc_out<<<1, 256, 0, stream>>>(h1b, d_in[9], d_in[10], flags, (float*)d_out);
}

// Round 6
// 9228.358 us; speedup vs baseline: 1.7837x; 1.7837x over previous
//
#include <hip/hip_runtime.h>

typedef __attribute__((ext_vector_type(8))) short bf8v;   // 8 x bf16
typedef __attribute__((ext_vector_type(4))) float fx4;    // MFMA accumulator
typedef unsigned short u16;
typedef unsigned int u32;

constexpr int SP = 1032;     // padded LDS row stride in elements (16B-aligned rows, spread banks)

__device__ __forceinline__ float b2f(u16 h) {
    u32 u = ((u32)h) << 16; float f; __builtin_memcpy(&f, &u, 4); return f;
}
__device__ __forceinline__ u16 f2b(float f) {
    u32 u; __builtin_memcpy(&u, &f, 4);
    return (u16)((u + 0x7fffu + ((u >> 16) & 1u)) >> 16);
}

// runtime-dtype scalar / 8-wide loads (one-time paths only)
__device__ __forceinline__ float ldsc(const void* p, long off, bool f32) {
    return f32 ? ((const float*)p)[off] : b2f(((const u16*)p)[off]);
}
__device__ __forceinline__ bf8v ld8cv(const void* p, long off, bool f32) {
    if (!f32) return *(const bf8v*)((const u16*)p + off);
    const float* f = (const float*)p + off;
    bf8v r;
#pragma unroll
    for (int j = 0; j < 8; ++j) r[j] = (short)f2b(f[j]);
    return r;
}

__device__ __forceinline__ float gru_out(float sr, float sz, float sn, float xn,
                                         float bxr, float bxz, float bxn,
                                         float bhr, float bhz, float bhn, float hp) {
    float r = 1.f / (1.f + __expf(-(sr + bxr + bhr)));
    float z = 1.f / (1.f + __expf(-(sz + bxz + bhz)));
    float pn = xn + bxn + r * (sn + bhn);
    pn = fminf(fmaxf(pn, -15.f), 15.f);
    float e = __expf(2.f * pn);
    float n = (e - 1.f) / (e + 1.f);
    return n + z * (hp - n);
}

// ---------------------------------------------------------------- zero helpers
__global__ __launch_bounds__(256) void zero_a(uint4* __restrict__ p) {    // 32 blocks: 131072 B (zbuf)
    p[(long)blockIdx.x * 256 + threadIdx.x] = make_uint4(0u, 0u, 0u, 0u);
}
__global__ __launch_bounds__(256) void zero_misc(uint4* __restrict__ p) { // 5 blocks: 20480 B (misc+bflags)
    p[(long)blockIdx.x * 256 + threadIdx.x] = make_uint4(0u, 0u, 0u, 0u);
}

// ---------------------------------------------------------------- flags[0]: 1 = inputs fp32
__global__ __launch_bounds__(256) void detect_dtype(const u32* __restrict__ x,
                                                    u32* __restrict__ flags) {
    __shared__ int red[256];
    int t = threadIdx.x;
    int cnt = 0;
    for (int i = t; i < 4096; i += 256) {
        u32 ex = (x[i] >> 7) & 0xff;
        cnt += (ex >= 100 && ex <= 135) ? 1 : 0;
    }
    red[t] = cnt; __syncthreads();
    for (int s = 128; s > 0; s >>= 1) { if (t < s) red[t] += red[t + s]; __syncthreads(); }
    if (t == 0) flags[0] = (red[0] < 2048) ? 1u : 0u;
}

// ---------------------------------------------------------------- x -> bf16 once (layout preserved)
__global__ __launch_bounds__(256) void conv_x(const void* __restrict__ x, u16* __restrict__ xc,
                                              const u32* __restrict__ flags) {
    bool f32 = flags[0] != 0;
    long i = ((long)blockIdx.x * 256 + threadIdx.x) * 8;
    if (f32) {
        const float* xf = (const float*)x + i;
        union { u16 o[8]; uint4 v; } u;
#pragma unroll
        for (int j = 0; j < 8; ++j) u.o[j] = f2b(xf[j]);
        *(uint4*)&xc[i] = u.v;
    } else {
        *(uint4*)&xc[i] = *(const uint4*)((const u16*)x + i);
    }
}

// ---------------------------------------------------------------- contention-free grid barrier (256 blocks)
// RELAXED spin-polls (no per-poll L2 invalidate — agent-acquire in a spin loop wipes the
// XCD L2 every iteration, the round-5 diagnosis), then ONE closing acquire load to
// establish synchronization (single invalidate per barrier). Release stores unchanged.
// Bounded spins (deadlock insurance): completes-with-wrong-results instead of hanging.
__device__ __forceinline__ u32 ldrel(const u32* p) {
    return __hip_atomic_load(p, __ATOMIC_RELAXED, __HIP_MEMORY_SCOPE_AGENT);
}
__device__ __forceinline__ void gbar(u32* bflags, u32* gen, u32 target, int& degraded) {
    const int LIM = degraded ? (1 << 12) : (1 << 20);
    __syncthreads();
    if (threadIdx.x == 0)
        __hip_atomic_store(&bflags[(u32)blockIdx.x * 16u], target,
                           __ATOMIC_RELEASE, __HIP_MEMORY_SCOPE_AGENT);
    if (blockIdx.x == 0) {
        int it = 0;
        while (ldrel(&bflags[(u32)threadIdx.x * 16u]) < target) {
            __builtin_amdgcn_s_sleep(1);
            if (++it > LIM) { degraded = 1; break; }
        }
        (void)__hip_atomic_load(&bflags[(u32)threadIdx.x * 16u],
                                __ATOMIC_ACQUIRE, __HIP_MEMORY_SCOPE_AGENT);
        __syncthreads();
        if (threadIdx.x == 0)
            __hip_atomic_store(gen, target, __ATOMIC_RELEASE, __HIP_MEMORY_SCOPE_AGENT);
    }
    if (threadIdx.x == 0) {
        int it = 0;
        while (ldrel(gen) < target) {
            __builtin_amdgcn_s_sleep(2);
            if (++it > LIM) { degraded = 1; break; }
        }
        (void)__hip_atomic_load(gen, __ATOMIC_ACQUIRE, __HIP_MEMORY_SCOPE_AGENT);
    }
    __syncthreads();
}

// ================================================================ per-timestep worker
// LDS bands (48 rows x SP, bf16, units u0..u0+7 of this block):
//   rows  0..15 : Wh [r(0-7) | z(8-15)]
//   rows 16..31 : Wx [r(0-7) | z(8-15)]
//   rows 32..47 : N  [Whn(0-7) | Wxn(8-15)]
// MFMA 16x16x32: A row = batch (l15), B col = l15, acc row = lk*4+reg, col = l15.
// accRZ = h@WhRZ + x@WxRZ (cols: 0-7 = sr, 8-15 = sz)
// accNH = h@N (cols 0-7 = sn valid) ; accNX = x@N (cols 8-15 = xn valid)
// Prefetch depth 8 (16 outstanding 16B loads/wave): with 1 wave/SIMD and post-barrier
// cold L2 (agent coherence), exposure ~= L3 latency / depth — depth 4 measured 32us/iter.
template<bool XF32>
__device__ __forceinline__ void gru_step(const short* __restrict__ Wlds,
    const u16* __restrict__ hprev, u16* __restrict__ hout,
    const void* __restrict__ xsrc, long xrow, long hrow,
    int l15, int lk, int bb, int u0,
    float Bxr, float Bxz, float Bxn, float Bhr, float Bhz, float Bhn)
{
    const int koff = lk * 8;

    bf8v bh[8], bx[8];
#pragma unroll
    for (int p = 0; p < 8; ++p) {
        bh[p] = *(const bf8v*)&hprev[hrow + p * 32 + koff];
        if constexpr (XF32) {
            const float* xf = (const float*)xsrc + xrow + p * 32 + koff;
            bf8v tv;
#pragma unroll
            for (int j = 0; j < 8; ++j) tv[j] = (short)f2b(xf[j]);
            bx[p] = tv;
        } else {
            bx[p] = *(const bf8v*)((const u16*)xsrc + xrow + p * 32 + koff);
        }
    }

    fx4 accRZ = {0.f, 0.f, 0.f, 0.f};
    fx4 accNH = {0.f, 0.f, 0.f, 0.f};
    fx4 accNX = {0.f, 0.f, 0.f, 0.f};

#pragma unroll
    for (int i = 0; i < 32; ++i) {
        const int kk = i * 32;
        bf8v rzH = *(const bf8v*)&Wlds[l15 * SP + kk + koff];
        bf8v rzX = *(const bf8v*)&Wlds[(16 + l15) * SP + kk + koff];
        bf8v nW  = *(const bf8v*)&Wlds[(32 + l15) * SP + kk + koff];
        bf8v aH = bh[i & 7], aX = bx[i & 7];
        if (i + 8 < 32) {                       // 8-deep prefetch
            bh[i & 7] = *(const bf8v*)&hprev[hrow + kk + 256 + koff];
            if constexpr (XF32) {
                const float* xf = (const float*)xsrc + xrow + kk + 256 + koff;
                bf8v tv;
#pragma unroll
                for (int j = 0; j < 8; ++j) tv[j] = (short)f2b(xf[j]);
                bx[i & 7] = tv;
            } else {
                bx[i & 7] = *(const bf8v*)((const u16*)xsrc + xrow + kk + 256 + koff);
            }
        }
        accRZ = __builtin_amdgcn_mfma_f32_16x16x32_bf16(aH, rzH, accRZ, 0, 0, 0);
        accRZ = __builtin_amdgcn_mfma_f32_16x16x32_bf16(aX, rzX, accRZ, 0, 0, 0);
        accNH = __builtin_amdgcn_mfma_f32_16x16x32_bf16(aH, nW,  accNH, 0, 0, 0);
        accNX = __builtin_amdgcn_mfma_f32_16x16x32_bf16(aX, nW,  accNX, 0, 0, 0);
    }

#pragma unroll
    for (int reg = 0; reg < 4; ++reg) {
        float sz = __shfl_xor(accRZ[reg], 8);   // z-gate from lane l15+8
        float xn = __shfl_xor(accNX[reg], 8);   // x@Wxn from lane l15+8
        if (l15 < 8) {
            const int bi = bb + lk * 4 + reg;
            const long ho = (long)bi * 1024 + u0 + l15;
            float hp = b2f(hprev[ho]);
            float hv = gru_out(accRZ[reg], sz, accNH[reg], xn,
                               Bxr, Bxz, Bxn, Bhr, Bhz, Bhn, hp);
            // nt store: h has zero cross-iteration L2 reuse (L2 invalidated each barrier);
            // avoid dirtying L2 and paying writeback in the release.
            __builtin_nontemporal_store(f2b(hv), &hout[ho]);
        }
    }
}

// ================================================================ persistent two-layer GRU
// 256 blocks x 256 threads, 1 block/CU (99 KB LDS). blk: layer = blk>>7, units u0 = (blk&127)*8.
// Weights LDS-resident (staged once, fp32->bf16 converted at load). Waves = 4 batch quarters.
// Time-skew: iteration s = layer0 step s, layer1 step s-1; one grid barrier per iteration.
__device__ void persist_impl(short* Wlds, bool wf32, bool xf32,
    const void* x, const u16* x16,
    const void* Wx0, const void* Wh0, const void* bx0, const void* bh0,
    const void* Wx1, const void* Wh1, const void* bx1, const void* bh1,
    const u16* zbuf, u16* h0a, u16* h0b, u16* h1a, u16* h1b,
    u32* bflags, u32* gen)
{
    const int blk = blockIdx.x;
    const int layer = blk >> 7;
    const int u0 = (blk & 127) * 8;
    const int tid = threadIdx.x;
    const int l = tid & 63, l15 = l & 15, lk = l >> 4;
    const int w = tid >> 6, bb = w * 16;

    const void* Wh  = layer ? Wh1 : Wh0;
    const void* Wx  = layer ? Wx1 : Wx0;
    const void* bxp = layer ? bx1 : bx0;
    const void* bhp = layer ? bh1 : bh0;

    // ---- stage weight slice into LDS once (16 rz-rows x 128 chunks of 8)
    for (int c = tid; c < 16 * 128; c += 256) {
        int r = c >> 7;                 // 0..15
        int kc = (c & 127) * 8;
        int g = r >> 3, j = r & 7;      // g: 0=r-gate, 1=z-gate
        long go = (long)(g * 1024 + u0 + j) * 1024 + kc;
        *(bf8v*)&Wlds[r * SP + kc]        = ld8cv(Wh, go, wf32);
        *(bf8v*)&Wlds[(16 + r) * SP + kc] = ld8cv(Wx, go, wf32);
        long gn = (long)(2048 + u0 + j) * 1024 + kc;          // n-gate row
        const void* Wn = (r < 8) ? Wh : Wx;                   // [Whn | Wxn] packed band
        *(bf8v*)&Wlds[(32 + r) * SP + kc] = ld8cv(Wn, gn, wf32);
    }

    // ---- hoist biases (per-lane unit u0 + (l15&7))
    const int uu = u0 + (l15 & 7);
    float Bxr = ldsc(bxp, uu, wf32),        Bhr = ldsc(bhp, uu, wf32);
    float Bxz = ldsc(bxp, 1024 + uu, wf32), Bhz = ldsc(bhp, 1024 + uu, wf32);
    float Bxn = ldsc(bxp, 2048 + uu, wf32), Bhn = ldsc(bhp, 2048 + uu, wf32);
    __syncthreads();

    u16* h0buf[2] = { h0a, h0b };
    u16* h1buf[2] = { h1a, h1b };
    const long hrow = (long)(bb + l15) * 1024;
    int degraded = 0;

    for (int s = 0; s <= 512; ++s) {
        const int t = layer ? (s - 1) : s;
        const bool active = layer ? (s >= 1) : (s < 512);
        if (active) {
            const u16* hprev = (t == 0) ? zbuf
                             : (layer ? h1buf[(t + 1) & 1] : h0buf[(t + 1) & 1]);
            u16* hout = layer ? h1buf[t & 1] : h0buf[t & 1];
            if (layer) {
                gru_step<false>(Wlds, hprev, hout, h0buf[t & 1], hrow, hrow,
                                l15, lk, bb, u0, Bxr, Bxz, Bxn, Bhr, Bhz, Bhn);
            } else {
                const long xrow = ((long)(bb + l15) * 512 + t) * 1024;
                if (xf32)
                    gru_step<true>(Wlds, hprev, hout, x, xrow, hrow,
                                   l15, lk, bb, u0, Bxr, Bxz, Bxn, Bhr, Bhz, Bhn);
                else
                    gru_step<false>(Wlds, hprev, hout, x16, xrow, hrow,
                                    l15, lk, bb, u0, Bxr, Bxz, Bxn, Bhr, Bhz, Bhn);
            }
        }
        gbar(bflags, gen, (u32)(s + 1), degraded);
    }
}

__global__ __launch_bounds__(256, 1) void gru_persist(const void* x, const u16* xc, int xconv,
    const void* Wx0, const void* Wh0, const void* bx0, const void* bh0,
    const void* Wx1, const void* Wh1, const void* bx1, const void* bh1,
    const u16* zbuf, u16* h0a, u16* h0b, u16* h1a, u16* h1b,
    const u32* flags, u32* bflags, u32* gen)
{
    __shared__ __align__(16) short Wlds[48 * SP];    // 99072 B -> 1 block/CU
    bool wf32 = flags[0] != 0;
    bool xf32 = wf32 && !xconv;                      // fallback: stream fp32 x with on-the-fly convert
    const u16* x16 = xconv ? xc : (const u16*)x;
    persist_impl(Wlds, wf32, xf32, x, x16,
                 Wx0, Wh0, bx0, bh0, Wx1, Wh1, bx1, bh1,
                 zbuf, h0a, h0b, h1a, h1b, bflags, gen);
}

// ---------------------------------------------------------------- final FC: fp32 output
__global__ __launch_bounds__(256) void fc_out(const u16* __restrict__ h,
                                              const void* __restrict__ fcW,
                                              const void* __restrict__ fcb,
                                              const u32* __restrict__ flags,
                                              float* __restrict__ out) {
    bool f32 = flags[0] != 0;
    __shared__ float red[256];
    int t = threadIdx.x, b = t >> 2, q = t & 3;
    float s = 0.f;
    for (int u = q * 256; u < q * 256 + 256; ++u) {
        float wv = f32 ? ((const float*)fcW)[u] : b2f(((const u16*)fcW)[u]);
        s += b2f(h[(long)b * 1024 + u]) * wv;
    }
    red[t] = s; __syncthreads();
    if (q == 0) {
        float fb = f32 ? ((const float*)fcb)[0] : b2f(((const u16*)fcb)[0]);
        out[b] = red[t] + red[t + 1] + red[t + 2] + red[t + 3] + fb;
    }
}

// ================================================================ host
extern "C" void kernel_launch(void* const* d_in, const int* in_sizes, int n_in,
                              void* d_out, int out_size, void* d_ws, size_t ws_size,
                              hipStream_t stream) {
    (void)in_sizes; (void)n_in; (void)out_size;
    char* ws = (char*)d_ws;
    u16* zbuf = (u16*)ws;                  // 131072 B zeros (initial h)
    u16* h0a  = (u16*)(ws + 131072);
    u16* h0b  = (u16*)(ws + 262144);
    u16* h1a  = (u16*)(ws + 393216);
    u16* h1b  = (u16*)(ws + 524288);
    u32* misc = (u32*)(ws + 655360);       // 4096 B: flags + gen
    u32* flags = misc;                     // [0..7]
    u32* gen   = misc + 16;                // own cacheline
    u32* bflags = (u32*)(ws + 659456);     // 16384 B: 256 flags x 64 B stride
    u16* xc    = (u16*)(ws + 675840);      // 67108864 B: bf16 x (optional)
    const size_t NEED = 675840ull + 67108864ull;
    const int xconv = (ws_size >= NEED) ? 1 : 0;

    zero_a<<<32, 256, 0, stream>>>((uint4*)d_ws);
    zero_misc<<<5, 256, 0, stream>>>((uint4*)(ws + 655360));
    detect_dtype<<<1, 256, 0, stream>>>((const u32*)d_in[0], flags);
    if (xconv) conv_x<<<16384, 256, 0, stream>>>(d_in[0], xc, flags);

    gru_persist<<<256, 256, 0, stream>>>(d_in[0], xc, xconv,
        d_in[1], d_in[3], d_in[2], d_in[4],      // Wx0, Wh0, bx0, bh0
        d_in[5], d_in[7], d_in[6], d_in[8],      // Wx1, Wh1, bx1, bh1
        zbuf, h0a, h0b, h1a, h1b, flags, bflags, gen);

    fc_out<<<1, 256, 0, stream>>>(h1b, d_in[9], d_in[10], flags, (float*)d_out);
}